// Round 5
// baseline (161.453 us; speedup 1.0000x reference)
//
#include <hip/hip_runtime.h>

// ChebGraphConv as ONE flat GEMM (K=192) over contiguous rows r = bt*1024+n:
//   out[r][o] = sum_{k,c} (d_k[n(r)] * x[r][c]) * Theta[k][c][o] + sum_k bias[k][o]
// R5: o-split waves. Each wave handles 16 rows x 32 o-columns per iter, so it
// holds only 12 W-frags (48 VGPR) -> ~4 waves/SIMD occupancy (R3/R4 held 24
// frags = 96 regs -> 2 waves/SIMD, the occupancy killer). No LDS, no barriers.
// Depth-2 ping-pong software pipeline on x loads. Duplicate x reads between
// o-half waves are served by per-CU L1.
// B=32,T=24,N=1024 -> 786432 rows. C_IN=C_OUT=64, K_cheb=3.

#define NNODES 1024
#define ROWS_PER_BLOCK 512
#define NBLOCKS 1536            // 786432 / 512

// ws layout (40.25 KB total)
#define WS_W  0                 // 24 frags * 64 lanes * 16B = 24 KB (bf16)
#define WS_BS (24 * 1024)       // 64 * f32 summed bias
#define WS_DV (24 * 1024 + 256) // 1024 * f32x4 {d0,d1,d2,0}

typedef __attribute__((ext_vector_type(8))) short  short8;  // 8 x bf16 MFMA frag
typedef __attribute__((ext_vector_type(4))) float  f32x4;   // MFMA C/D frag

// round-to-nearest-even f32 -> bf16 bits
__device__ __forceinline__ unsigned short f2bf(float f) {
    union { float f; unsigned u; } v; v.f = f;
    unsigned r = v.u + 0x7FFFu + ((v.u >> 16) & 1u);
    return (unsigned short)(r >> 16);
}

__global__ void cheb_prep(const float* __restrict__ Tks,
                          const float* __restrict__ Theta,
                          const float* __restrict__ bias,
                          unsigned char* __restrict__ ws) {
    const int b = blockIdx.x;
    const int l = threadIdx.x;   // 64 threads
    if (b < 24) {
        // frag f = (kc*2+h)*4 + nb ; lane l holds W^T row o = nb*16+(l&15),
        // k-slice c = h*32 + (l>>4)*8 + j, j=0..7  (A-operand layout, 16x16x32)
        const int kc = b >> 3, h = (b >> 2) & 1, nb = b & 3;
        const int o  = nb * 16 + (l & 15);
        const int cb = h * 32 + (l >> 4) * 8;
        unsigned short* dst = (unsigned short*)(ws + WS_W) + ((size_t)b * 64 + l) * 8;
        #pragma unroll
        for (int j = 0; j < 8; ++j)
            dst[j] = f2bf(Theta[kc * 4096 + (cb + j) * 64 + o]);
    } else if (b < 40) {
        const int n = (b - 24) * 64 + l;
        const size_t dg = (size_t)n * (NNODES + 1);
        f32x4 v;
        v[0] = Tks[dg];
        v[1] = Tks[(size_t)NNODES * NNODES + dg];
        v[2] = Tks[(size_t)2 * NNODES * NNODES + dg];
        v[3] = 0.0f;
        *((f32x4*)(ws + WS_DV) + n) = v;
    } else {
        float* bs = (float*)(ws + WS_BS);
        bs[l] = bias[l] + bias[64 + l] + bias[128 + l];
    }
}

__global__ __launch_bounds__(256, 4) void cheb_main(
    const float* __restrict__ x,          // [786432 * 64]
    const unsigned char* __restrict__ ws,
    float* __restrict__ out)              // [786432 * 64]
{
    const int tid  = threadIdx.x;
    const int wave = tid >> 6;
    const int lane = tid & 63;
    const int lrow = lane & 15;   // B col (= bt-row) / D col
    const int lgrp = lane >> 4;   // frag k-subgroup / D o-subgroup
    const int wr   = wave >> 1;   // which 16-row half of the 32-row iter
    const int q    = wave & 1;    // which 32-wide o-half
    const int laneoff = wr * 16 + lrow;
    const int rowbase = blockIdx.x * ROWS_PER_BLOCK;

    const unsigned short* wimg = (const unsigned short*)(ws + WS_W);
    const float*          bsum = (const float*)(ws + WS_BS);
    const f32x4*          dvec = (const f32x4*)(ws + WS_DV);

    // ---- per-wave constants: 12 W-frags for this o-half (48 VGPR, L2-hot) ----
    short8 wf[3][2][2];
    #pragma unroll
    for (int kc = 0; kc < 3; ++kc)
        #pragma unroll
        for (int h = 0; h < 2; ++h)
            #pragma unroll
            for (int nb = 0; nb < 2; ++nb)
                wf[kc][h][nb] = *(const short8*)(
                    wimg + ((size_t)(((kc * 2 + h) * 4 + 2 * q + nb) * 64 + lane)) * 8);

    f32x4 bs4[2];
    #pragma unroll
    for (int nb = 0; nb < 2; ++nb)
        bs4[nb] = *(const f32x4*)(bsum + q * 32 + nb * 16 + lgrp * 4);

#define LOADX(G, X0, X1, X2, X3, DV) do {                                    \
        const int row_ = rowbase + (G) * 32 + laneoff;                       \
        const float* xr_ = x + (size_t)row_ * 64;                            \
        X0 = *(const f32x4*)(xr_ + lgrp * 8);                                \
        X1 = *(const f32x4*)(xr_ + lgrp * 8 + 4);                            \
        X2 = *(const f32x4*)(xr_ + 32 + lgrp * 8);                           \
        X3 = *(const f32x4*)(xr_ + 32 + lgrp * 8 + 4);                       \
        DV = dvec[row_ & (NNODES - 1)];                                      \
    } while (0)

#define COMPUTE(G, X0, X1, X2, X3, DV) do {                                  \
        short8 xf[3][2];                                                     \
        _Pragma("unroll")                                                    \
        for (int kc = 0; kc < 3; ++kc) {                                     \
            const float dk = DV[kc];                                         \
            _Pragma("unroll")                                                \
            for (int j = 0; j < 4; ++j) {                                    \
                xf[kc][0][j]     = (short)f2bf(dk * X0[j]);                  \
                xf[kc][0][4 + j] = (short)f2bf(dk * X1[j]);                  \
                xf[kc][1][j]     = (short)f2bf(dk * X2[j]);                  \
                xf[kc][1][4 + j] = (short)f2bf(dk * X3[j]);                  \
            }                                                                \
        }                                                                    \
        f32x4 acc[2] = {f32x4{0,0,0,0}, f32x4{0,0,0,0}};                     \
        _Pragma("unroll")                                                    \
        for (int kc = 0; kc < 3; ++kc)                                       \
            _Pragma("unroll")                                                \
            for (int h = 0; h < 2; ++h)                                      \
                _Pragma("unroll")                                            \
                for (int nb = 0; nb < 2; ++nb)                               \
                    acc[nb] = __builtin_amdgcn_mfma_f32_16x16x32_bf16(       \
                        wf[kc][h][nb], xf[kc][h], acc[nb], 0, 0, 0);         \
        float* orow = out + (size_t)(rowbase + (G) * 32 + laneoff) * 64      \
                          + q * 32;                                          \
        _Pragma("unroll")                                                    \
        for (int nb = 0; nb < 2; ++nb) {                                     \
            f32x4 o4;                                                        \
            _Pragma("unroll")                                                \
            for (int j = 0; j < 4; ++j) o4[j] = acc[nb][j] + bs4[nb][j];     \
            *(f32x4*)(orow + nb * 16 + lgrp * 4) = o4;                       \
        }                                                                    \
    } while (0)

    // ---- 16 iters of 32 rows, depth-2 ping-pong (static names, rule #20) ----
    f32x4 xa0, xa1, xa2, xa3, da;
    f32x4 xb0, xb1, xb2, xb3, db;

    LOADX(0, xa0, xa1, xa2, xa3, da);
    LOADX(1, xb0, xb1, xb2, xb3, db);
    #pragma unroll 1
    for (int i = 0; i < 7; ++i) {
        COMPUTE(2 * i,     xa0, xa1, xa2, xa3, da);
        LOADX(2 * i + 2,   xa0, xa1, xa2, xa3, da);
        COMPUTE(2 * i + 1, xb0, xb1, xb2, xb3, db);
        LOADX(2 * i + 3,   xb0, xb1, xb2, xb3, db);
    }
    COMPUTE(14, xa0, xa1, xa2, xa3, da);
    COMPUTE(15, xb0, xb1, xb2, xb3, db);

#undef LOADX
#undef COMPUTE
}

extern "C" void kernel_launch(void* const* d_in, const int* in_sizes, int n_in,
                              void* d_out, int out_size, void* d_ws, size_t ws_size,
                              hipStream_t stream) {
    const float* x     = (const float*)d_in[0];
    const float* Tks   = (const float*)d_in[1];
    const float* Theta = (const float*)d_in[2];
    const float* bias  = (const float*)d_in[3];
    float* out = (float*)d_out;
    unsigned char* ws = (unsigned char*)d_ws;

    hipLaunchKernelGGL(cheb_prep, dim3(41), dim3(64), 0, stream,
                       Tks, Theta, bias, ws);
    hipLaunchKernelGGL(cheb_main, dim3(NBLOCKS), dim3(256), 0, stream,
                       x, ws, out);
}

// Round 6
// 92.433 us; speedup vs baseline: 1.7467x; 1.7467x over previous
//
#include <hip/hip_runtime.h>

// ChebGraphConv as ONE flat GEMM (K=192) over contiguous rows r = bt*1024+n:
//   out[r][o] = sum_{k,c} (d_k[n(r)] * x[r][c]) * Theta[k][c][o] + sum_k bias[k][o]
// R6: DENSE per-instruction memory access. x is staged to LDS with
// global_load_lds (each instr = contiguous 1KB = 16 full 64B lines), with the
// global source pre-swizzled (col ^= (row&7)<<4) so swizzled ds_read_b128 frag
// reads hit all 32 banks. Double-buffered tiles, depth-1 prefetch. bf16
// conversion via v_cvt_pk_bf16_f32 (1 instr / 2 elems). W-frags in registers.
// B=32,T=24,N=1024 -> 786432 rows. C_IN=C_OUT=64, K_cheb=3.

#define NNODES 1024
#define TILE_ROWS 64
#define NTILES 8
#define ROWS_PER_BLOCK (TILE_ROWS * NTILES)     // 512
#define NBLOCKS (786432 / ROWS_PER_BLOCK)       // 1536

// ws layout
#define WS_W  0                  // 24 frags * 64 lanes * 16B = 24 KB (bf16)
#define WS_BS (24 * 1024)        // 64 * f32 summed bias
#define WS_DV (24 * 1024 + 256)  // 1024 * f32x4 {d0,d1,d2,0}

typedef __attribute__((ext_vector_type(8))) short short8;  // 8 x bf16 MFMA frag
typedef __attribute__((ext_vector_type(4))) float f32x4;   // MFMA C/D frag
typedef __attribute__((ext_vector_type(4))) int   i32x4;

// round-to-nearest-even f32 -> bf16 bits (prep kernel only)
__device__ __forceinline__ unsigned short f2bf(float f) {
    union { float f; unsigned u; } v; v.f = f;
    unsigned r = v.u + 0x7FFFu + ((v.u >> 16) & 1u);
    return (unsigned short)(r >> 16);
}

// pack 2 f32 -> 2 bf16 in one VALU op
__device__ __forceinline__ int cvt_pk_bf16(float lo, float hi) {
    int r;
    asm("v_cvt_pk_bf16_f32 %0, %1, %2" : "=v"(r) : "v"(lo), "v"(hi));
    return r;
}

// dense global->LDS: wave-uniform LDS base, lane l lands at base + l*16
__device__ __forceinline__ void gload_lds16(const void* g, void* l) {
    __builtin_amdgcn_global_load_lds(
        (const __attribute__((address_space(1))) void*)g,
        (__attribute__((address_space(3))) void*)l,
        16, 0, 0);
}

__global__ void cheb_prep(const float* __restrict__ Tks,
                          const float* __restrict__ Theta,
                          const float* __restrict__ bias,
                          unsigned char* __restrict__ ws) {
    const int b = blockIdx.x;
    const int l = threadIdx.x;   // 64 threads
    if (b < 24) {
        // frag f = (kc*2+h)*4 + nb ; lane l holds W^T row o = nb*16+(l&15),
        // k-slice c = h*32 + (l>>4)*8 + j  (A-operand layout, 16x16x32)
        const int kc = b >> 3, h = (b >> 2) & 1, nb = b & 3;
        const int o  = nb * 16 + (l & 15);
        const int cb = h * 32 + (l >> 4) * 8;
        unsigned short* dst = (unsigned short*)(ws + WS_W) + ((size_t)b * 64 + l) * 8;
        #pragma unroll
        for (int j = 0; j < 8; ++j)
            dst[j] = f2bf(Theta[kc * 4096 + (cb + j) * 64 + o]);
    } else if (b < 40) {
        const int n = (b - 24) * 64 + l;
        const size_t dg = (size_t)n * (NNODES + 1);
        f32x4 v;
        v[0] = Tks[dg];
        v[1] = Tks[(size_t)NNODES * NNODES + dg];
        v[2] = Tks[(size_t)2 * NNODES * NNODES + dg];
        v[3] = 0.0f;
        *((f32x4*)(ws + WS_DV) + n) = v;
    } else {
        float* bs = (float*)(ws + WS_BS);
        bs[l] = bias[l] + bias[64 + l] + bias[128 + l];
    }
}

__global__ __launch_bounds__(256) void cheb_main(
    const float* __restrict__ x,          // [786432 * 64]
    const unsigned char* __restrict__ ws,
    float* __restrict__ out)              // [786432 * 64]
{
    __shared__ float xs[2][TILE_ROWS * 64];   // 2 x 16 KB, swizzled image of x tile

    const int tid  = threadIdx.x;
    const int wave = tid >> 6;
    const int lane = tid & 63;
    const int lrow = lane & 15;
    const int lgrp = lane >> 4;
    const size_t rowbase = (size_t)blockIdx.x * ROWS_PER_BLOCK;

    const unsigned short* wimg = (const unsigned short*)(ws + WS_W);
    const float*          bsum = (const float*)(ws + WS_BS);
    const f32x4*          dvec = (const f32x4*)(ws + WS_DV);

    // ---- per-wave constants: 24 W-frags (coalesced dwordx4, L2-hot) ----
    short8 wf[3][2][4];
    #pragma unroll
    for (int kc = 0; kc < 3; ++kc)
        #pragma unroll
        for (int h = 0; h < 2; ++h)
            #pragma unroll
            for (int nb = 0; nb < 4; ++nb)
                wf[kc][h][nb] = *(const short8*)(
                    wimg + ((size_t)(((kc * 2 + h) * 4 + nb) * 64 + lane)) * 8);

    f32x4 bs4[4];
    #pragma unroll
    for (int nb = 0; nb < 4; ++nb)
        bs4[nb] = *(const f32x4*)(bsum + nb * 16 + lgrp * 4);

    // ---- stage tile t into buffer b: 16 x 1KB dense chunks, source swizzled ----
    // chunk u covers tile rows 4u..4u+3; lane l -> LDS byte u*1024 + l*16,
    // i.e. tile (R = 4u + (l>>4), col C = (l&15)*16); source col = C ^ ((R&7)<<4)
#define STAGE(T, B) do {                                                      \
        _Pragma("unroll")                                                     \
        for (int s = 0; s < 4; ++s) {                                         \
            const int u_ = wave * 4 + s;                                      \
            const int R_ = u_ * 4 + lgrp;                                     \
            const int c_ = (lrow * 16) ^ ((R_ & 7) << 4);                     \
            const char* g_ = (const char*)x +                                 \
                (((rowbase + (size_t)(T) * TILE_ROWS + R_) << 8) + c_);       \
            gload_lds16(g_, &xs[B][u_ * 256]);                                \
        }                                                                     \
    } while (0)

    STAGE(0, 0);
    __syncthreads();

    #pragma unroll 1
    for (int t = 0; t < NTILES; ++t) {
        const int cur = t & 1;
        if (t + 1 < NTILES) STAGE(t + 1, cur ^ 1);

        // ---- read this wave's 16 rows from LDS (swizzled addresses) ----
        const int R = wave * 16 + lrow;
        const int m = (lrow & 7) << 4;
        const char* rowp = (const char*)&xs[cur][R * 64];
        const int c00 = (lgrp * 32) ^ m;
        const int c01 = (lgrp * 32 + 16) ^ m;
        const f32x4 x0 = *(const f32x4*)(rowp + c00);
        const f32x4 x1 = *(const f32x4*)(rowp + c01);
        const f32x4 x2 = *(const f32x4*)(rowp + 128 + c00);
        const f32x4 x3 = *(const f32x4*)(rowp + 128 + c01);

        const size_t grow = rowbase + (size_t)t * TILE_ROWS + R;
        const f32x4 dv = dvec[grow & (NNODES - 1)];

        // ---- build 6 B-frags: elem j of xf[kc][h] = bf16(d_kc * x[h*32+lgrp*8+j]) ----
        short8 xf[3][2];
        #pragma unroll
        for (int kc = 0; kc < 3; ++kc) {
            const float dk = dv[kc];
            i32x4 r0, r1;
            r0[0] = cvt_pk_bf16(dk * x0[0], dk * x0[1]);
            r0[1] = cvt_pk_bf16(dk * x0[2], dk * x0[3]);
            r0[2] = cvt_pk_bf16(dk * x1[0], dk * x1[1]);
            r0[3] = cvt_pk_bf16(dk * x1[2], dk * x1[3]);
            r1[0] = cvt_pk_bf16(dk * x2[0], dk * x2[1]);
            r1[1] = cvt_pk_bf16(dk * x2[2], dk * x2[3]);
            r1[2] = cvt_pk_bf16(dk * x3[0], dk * x3[1]);
            r1[3] = cvt_pk_bf16(dk * x3[2], dk * x3[3]);
            xf[kc][0] = __builtin_bit_cast(short8, r0);
            xf[kc][1] = __builtin_bit_cast(short8, r1);
        }

        f32x4 acc[4] = {f32x4{0,0,0,0}, f32x4{0,0,0,0},
                        f32x4{0,0,0,0}, f32x4{0,0,0,0}};
        #pragma unroll
        for (int kc = 0; kc < 3; ++kc)
            #pragma unroll
            for (int h = 0; h < 2; ++h)
                #pragma unroll
                for (int nb = 0; nb < 4; ++nb)
                    acc[nb] = __builtin_amdgcn_mfma_f32_16x16x32_bf16(
                        wf[kc][h][nb], xf[kc][h], acc[nb], 0, 0, 0);

        // ---- D: col(lane&15)=bt-row, row(lgrp*4+j)=o -> dwordx4 full-line stores ----
        float* orow = out + grow * 64;
        #pragma unroll
        for (int nb = 0; nb < 4; ++nb) {
            f32x4 o4;
            #pragma unroll
            for (int j = 0; j < 4; ++j) o4[j] = acc[nb][j] + bs4[nb][j];
            *(f32x4*)(orow + nb * 16 + lgrp * 4) = o4;
        }

        __syncthreads();
    }
#undef STAGE
}

extern "C" void kernel_launch(void* const* d_in, const int* in_sizes, int n_in,
                              void* d_out, int out_size, void* d_ws, size_t ws_size,
                              hipStream_t stream) {
    const float* x     = (const float*)d_in[0];
    const float* Tks   = (const float*)d_in[1];
    const float* Theta = (const float*)d_in[2];
    const float* bias  = (const float*)d_in[3];
    float* out = (float*)d_out;
    unsigned char* ws = (unsigned char*)d_ws;

    hipLaunchKernelGGL(cheb_prep, dim3(41), dim3(64), 0, stream,
                       Tks, Theta, bias, ws);
    hipLaunchKernelGGL(cheb_main, dim3(NBLOCKS), dim3(256), 0, stream,
                       x, ws, out);
}